// Round 6
// baseline (382.865 us; speedup 1.0000x reference)
//
#include <hip/hip_runtime.h>

namespace {

constexpr int Dn   = 128;
constexpr int DIN  = 512;
constexpr int Hn   = 8;
constexpr int Mn   = 128;
constexpr int DFF  = 512;
constexpr int Gn   = 8;     // batches per block (attention sequential per batch)
constexpr float ATT_SCALE = 0.25f;
constexpr float INV_SQRT2 = 0.70710678118654752440f;

__device__ __forceinline__ unsigned short f2bf(float f) {
    unsigned u = __float_as_uint(f);
    unsigned r = (u + 0x7fffu + ((u >> 16) & 1u)) >> 16;
    return (unsigned short)r;
}
__device__ __forceinline__ float bf2f(unsigned short s) {
    return __uint_as_float((unsigned)s << 16);
}

// dot of a 128-float global row with a 128-float LDS vector (broadcast v)
__device__ __forceinline__ float dot128(const float* __restrict__ wrow,
                                        const float* __restrict__ v)
{
    const float4* w4 = (const float4*)wrow;
    const float4* v4 = (const float4*)v;
    float acc = 0.f;
#pragma unroll
    for (int j = 0; j < 32; ++j) {
        float4 a = w4[j], b = v4[j];
        acc += a.x*b.x + a.y*b.y + a.z*b.z + a.w*b.w;
    }
    return acc;
}

// LayerNorm, 64 threads per row (one wave). In-place safe.
template <int NCOL>
__device__ __forceinline__ void ln_row64(const float* __restrict__ src,
                                         float* __restrict__ dst,
                                         const float* __restrict__ gw,
                                         const float* __restrict__ gb,
                                         const float* __restrict__ resid,
                                         int sub)
{
    constexpr int E = NCOL / 64;
    float v0[E]; float sm = 0.f;
#pragma unroll
    for (int i = 0; i < E; ++i) { v0[i] = src[sub*E + i]; sm += v0[i]; }
#pragma unroll
    for (int m = 32; m >= 1; m >>= 1) sm += __shfl_xor(sm, m);
    float mean = sm * (1.f / (float)NCOL);
    float vs = 0.f;
#pragma unroll
    for (int i = 0; i < E; ++i) { float d0 = v0[i] - mean; vs += d0*d0; }
#pragma unroll
    for (int m = 32; m >= 1; m >>= 1) vs += __shfl_xor(vs, m);
    float rstd = rsqrtf(vs * (1.f / (float)NCOL) + 1e-5f);
#pragma unroll
    for (int i = 0; i < E; ++i) {
        int d = sub*E + i;
        float r = (v0[i] - mean) * rstd * gw[d] + gb[d];
        dst[d] = resid ? (r + resid[d]) : r;
    }
}

__global__ __launch_bounds__(512, 2)
void fused_block(const float* __restrict__ x,
                 const float* __restrict__ W_in,
                 const float* __restrict__ b_in,
                 const float* __restrict__ pos,
                 const float* __restrict__ mask,
                 const float* __restrict__ mem,
                 const float* __restrict__ ln1_w, const float* __restrict__ ln1_b,
                 const float* __restrict__ W_qkv, const float* __restrict__ b_qkv,
                 const float* __restrict__ W_out, const float* __restrict__ b_out,
                 const float* __restrict__ ln2_w, const float* __restrict__ ln2_b,
                 const float* __restrict__ ln3_w, const float* __restrict__ ln3_b,
                 const float* __restrict__ W_ff1, const float* __restrict__ b_ff1,
                 const float* __restrict__ ln4_w, const float* __restrict__ ln4_b,
                 const float* __restrict__ W_ff2, const float* __restrict__ b_ff2,
                 const float* __restrict__ ln5_w, const float* __restrict__ ln5_b,
                 const float* __restrict__ W_head, const float* __restrict__ b_head,
                 float* __restrict__ out)
{
    const int t    = threadIdx.x;
    const int b0   = blockIdx.x * Gn;
    const int lane = t & 63;
    const int wv   = t >> 6;

    // 64KB multi-purpose: tile (swizzled) / P1+P6f partials / C-partials / f1
    __shared__ __align__(16) float s_mem[Mn * Dn];
    // A_t bf16 (2KB) -> qw fp32 [128][8] -> h-resid [8][128]
    __shared__ __align__(16) float s_A[1024];
    // s_q (aliased first 128) -> scores[128][9] (+rstd) -> ctxn[8][128] -> tail tmp
    __shared__ __align__(16) float s_sc[1152];
    __shared__ __align__(16) float s_lnq[128];
    __shared__ __align__(16) float s_qin[Gn][Dn];
    __shared__ __align__(16) unsigned short s_qo16[Gn][Dn];   // o in bf16
    __shared__ float s_s2c[Hn], s_s0[Hn], s_den[Hn], s_p0[Hn];

    float4* mem4 = (float4*)s_mem;
    unsigned short* s_At = (unsigned short*)s_A;
    float* s_q = s_sc;                     // alias (dead before scores written)

    //=== P1: q_in = x @ W_in^T + b_in + pos  (K-split-4, x read uniform) ===
    {
        int d = t & 127, kg = t >> 7;
        const float4* w4 = (const float4*)(W_in + (size_t)d * DIN) + kg*32;
        float acc[8] = {0,0,0,0,0,0,0,0};
        for (int j = 0; j < 32; ++j) {
            float4 a = w4[j];
#pragma unroll
            for (int g = 0; g < 8; ++g) {
                float4 xv = *(const float4*)(x + (size_t)(b0+g)*DIN + (size_t)(kg*32+j)*4);
                acc[g] = fmaf(a.x, xv.x, acc[g]); acc[g] = fmaf(a.y, xv.y, acc[g]);
                acc[g] = fmaf(a.z, xv.z, acc[g]); acc[g] = fmaf(a.w, xv.w, acc[g]);
            }
        }
#pragma unroll
        for (int g = 0; g < 8; ++g) s_mem[kg*1024 + d*8 + g] = acc[g];
    }
    __syncthreads();
    {
#pragma unroll
        for (int u = 0; u < 2; ++u) {
            int idx = t*2 + u; int d = idx >> 3, g = idx & 7;
            float v = s_mem[idx] + s_mem[1024 + idx] + s_mem[2048 + idx] + s_mem[3072 + idx];
            s_qin[g][d] = v + b_in[d] + pos[(size_t)(b0+g)*Dn + d];
        }
    }
    __syncthreads();

    //=== Attention: per batch, full tile in LDS ===========================
    for (int g = 0; g < Gn; ++g) {
        // S: stage swizzled tile; wave0: lnq; waves 2-3: q
        {
            const float4* src = (const float4*)(mem + (size_t)(b0+g) * Mn * Dn);
#pragma unroll
            for (int i = 0; i < 8; ++i) {
                int fid = t + 512*i;
                int r = fid >> 5, k = fid & 31;
                mem4[r*32 + (k ^ (r & 7))] = src[fid];
            }
            if (t < 64) {
                ln_row64<Dn>(&s_qin[g][0], s_lnq, ln1_w, ln1_b, nullptr, t);
            } else if (t >= 128 && t < 256) {
                int dd = t - 128;
                s_q[dd] = dot128(W_qkv + (size_t)dd*Dn, &s_qin[g][0]) + b_qkv[dd];
            }
        }
        __syncthreads();

        // Aq: A_t (bf16, s1-folded) + per-head scalars
        if (t < 256) {
            int h = t >> 5, js = t & 31;
            float aq[4] = {0,0,0,0};
            float ch = 0.f;
#pragma unroll
            for (int d0 = 0; d0 < 16; ++d0) {
                float qv = s_q[h*16 + d0];
                float4 w = ((const float4*)(W_qkv + (size_t)(Dn + h*16 + d0)*Dn))[js];
                aq[0] = fmaf(qv, w.x, aq[0]); aq[1] = fmaf(qv, w.y, aq[1]);
                aq[2] = fmaf(qv, w.z, aq[2]); aq[3] = fmaf(qv, w.w, aq[3]);
                ch = fmaf(qv, b_qkv[Dn + h*16 + d0], ch);
            }
            ch *= ATT_SCALE;
            float s1p = 0.f, s2p = 0.f, s0p = 0.f;
            float aqw[4];
#pragma unroll
            for (int c = 0; c < 4; ++c) {
                int j = js*4 + c;
                float a = ATT_SCALE * aq[c];
                aqw[c] = a * ln1_w[j];
                s1p += aqw[c];
                s2p = fmaf(a, ln1_b[j], s2p);
                s0p = fmaf(a, s_lnq[j], s0p);
            }
#pragma unroll
            for (int m = 16; m >= 1; m >>= 1) {
                s1p += __shfl_xor(s1p, m, 32);
                s2p += __shfl_xor(s2p, m, 32);
                s0p += __shfl_xor(s0p, m, 32);
            }
            float sub = s1p * (1.f/128.f);
#pragma unroll
            for (int c = 0; c < 4; ++c) {
                int j = js*4 + c;
                s_At[j*8 + h] = f2bf(aqw[c] - sub);
            }
            if (js == 0) { s_s2c[h] = s2p + ch; s_s0[h] = s0p + ch; }
        }
        __syncthreads();

        // A: raw head-dots + row stats (4 lanes/row, j-major bf16 A_t)
        {
            int r = t >> 2, hf = t & 3;
            float d8[8] = {0,0,0,0,0,0,0,0};
            float sum = 0.f, ssq = 0.f;
#pragma unroll
            for (int kk = 0; kk < 8; ++kk) {
                int k = hf*8 + kk;
                float4 v = mem4[r*32 + (k ^ (r & 7))];
                sum += v.x + v.y + v.z + v.w;
                ssq = fmaf(v.x, v.x, ssq); ssq = fmaf(v.y, v.y, ssq);
                ssq = fmaf(v.z, v.z, ssq); ssq = fmaf(v.w, v.w, ssq);
#pragma unroll
                for (int c = 0; c < 4; ++c) {
                    int j = k*4 + c;
                    uint4 au = *(const uint4*)&s_At[j*8];
                    float a0 = __uint_as_float(au.x << 16);
                    float a1 = __uint_as_float(au.x & 0xffff0000u);
                    float a2 = __uint_as_float(au.y << 16);
                    float a3 = __uint_as_float(au.y & 0xffff0000u);
                    float a4 = __uint_as_float(au.z << 16);
                    float a5 = __uint_as_float(au.z & 0xffff0000u);
                    float a6 = __uint_as_float(au.w << 16);
                    float a7 = __uint_as_float(au.w & 0xffff0000u);
                    float vc = (c == 0) ? v.x : (c == 1) ? v.y : (c == 2) ? v.z : v.w;
                    d8[0] = fmaf(a0, vc, d8[0]); d8[1] = fmaf(a1, vc, d8[1]);
                    d8[2] = fmaf(a2, vc, d8[2]); d8[3] = fmaf(a3, vc, d8[3]);
                    d8[4] = fmaf(a4, vc, d8[4]); d8[5] = fmaf(a5, vc, d8[5]);
                    d8[6] = fmaf(a6, vc, d8[6]); d8[7] = fmaf(a7, vc, d8[7]);
                }
            }
#pragma unroll
            for (int m = 1; m <= 2; m <<= 1) {
                sum += __shfl_xor(sum, m, 4);
                ssq += __shfl_xor(ssq, m, 4);
#pragma unroll
                for (int h = 0; h < 8; ++h) d8[h] += __shfl_xor(d8[h], m, 4);
            }
            if (hf == 0) {
                float mean = sum * (1.f/128.f);
                float var  = fmaf(-mean, mean, ssq * (1.f/128.f));
                float rstd = rsqrtf(var + 1e-5f);
#pragma unroll
                for (int h = 0; h < 8; ++h) s_sc[r*9 + h] = d8[h];
                s_sc[r*9 + 8] = rstd;
            }
        }
        __syncthreads();

        // SM: one-shot softmax per head (wave w = head w); write qw into s_A
        {
            int w = wv, l = lane;
            int r0 = 2*l, r1 = 2*l + 1;
            float raw0 = s_sc[r0*9 + w], rs0 = s_sc[r0*9 + 8];
            float raw1 = s_sc[r1*9 + w], rs1 = s_sc[r1*9 + 8];
            float mk0 = mask[(size_t)(b0+g)*Mn + r0];
            float mk1 = mask[(size_t)(b0+g)*Mn + r1];
            float sc0 = fmaf(rs0, raw0, s_s2c[w]) + mk0;
            float sc1 = fmaf(rs1, raw1, s_s2c[w]) + mk1;
            float mx = fmaxf(sc0, sc1);
#pragma unroll
            for (int m = 1; m < 64; m <<= 1) mx = fmaxf(mx, __shfl_xor(mx, m));
            mx = fmaxf(mx, s_s0[w]);
            float e0 = __expf(sc0 - mx), e1 = __expf(sc1 - mx);
            float ds = e0 + e1;
#pragma unroll
            for (int m = 1; m < 64; m <<= 1) ds += __shfl_xor(ds, m);
            float p0 = __expf(s_s0[w] - mx);
            s_A[r0*8 + w] = e0 * rs0;
            s_A[r1*8 + w] = e1 * rs1;
            if (l == 0) { s_den[w] = ds + p0; s_p0[w] = p0; }
        }
        __syncthreads();

        // C: ctx accumulation (wave w: rows 16w..16w+15; lane: cols 2l,2l+1)
        float ctx0[8], ctx1[8];
        {
            int w = wv, l = lane;
#pragma unroll
            for (int h = 0; h < 8; ++h) { ctx0[h] = 0.f; ctx1[h] = 0.f; }
#pragma unroll 4
            for (int rr = 0; rr < 16; ++rr) {
                int r = w*16 + rr;
                float4 qa = *(const float4*)&s_A[r*8];
                float4 qb = *(const float4*)&s_A[r*8 + 4];
                const float* bp = s_mem + r*Dn + (((l>>1) ^ (r & 7)) << 2) + (l & 1)*2;
                float2 mv = *(const float2*)bp;
                ctx0[0]=fmaf(qa.x,mv.x,ctx0[0]); ctx1[0]=fmaf(qa.x,mv.y,ctx1[0]);
                ctx0[1]=fmaf(qa.y,mv.x,ctx0[1]); ctx1[1]=fmaf(qa.y,mv.y,ctx1[1]);
                ctx0[2]=fmaf(qa.z,mv.x,ctx0[2]); ctx1[2]=fmaf(qa.z,mv.y,ctx1[2]);
                ctx0[3]=fmaf(qa.w,mv.x,ctx0[3]); ctx1[3]=fmaf(qa.w,mv.y,ctx1[3]);
                ctx0[4]=fmaf(qb.x,mv.x,ctx0[4]); ctx1[4]=fmaf(qb.x,mv.y,ctx1[4]);
                ctx0[5]=fmaf(qb.y,mv.x,ctx0[5]); ctx1[5]=fmaf(qb.y,mv.y,ctx1[5]);
                ctx0[6]=fmaf(qb.z,mv.x,ctx0[6]); ctx1[6]=fmaf(qb.z,mv.y,ctx1[6]);
                ctx0[7]=fmaf(qb.w,mv.x,ctx0[7]); ctx1[7]=fmaf(qb.w,mv.y,ctx1[7]);
            }
        }
        __syncthreads();   // all tile reads complete
        {
            int w = wv, l = lane;
            int lw = l ^ (w << 3);
#pragma unroll
            for (int h = 0; h < 8; ++h) {
                s_mem[(h*2+0)*512 + w*64 + lw] = ctx0[h];
                s_mem[(h*2+1)*512 + w*64 + lw] = ctx1[h];
            }
        }
        __syncthreads();
        // D: combine partials + verified-fold finish -> ctxn into s_sc
        {
            int w = wv, l = lane;
            float c0 = 0.f, c1 = 0.f;
#pragma unroll
            for (int w2 = 0; w2 < 8; ++w2) {
                int lw = l ^ (w2 << 3);
                c0 += s_mem[(w*2+0)*512 + w2*64 + lw];
                c1 += s_mem[(w*2+1)*512 + w2*64 + lw];
            }
            float rsum = c0 + c1;
#pragma unroll
            for (int m = 1; m < 64; m <<= 1) rsum += __shfl_xor(rsum, m);
            float cS  = rsum * (1.f/128.f);
            float den = s_den[w], p0 = s_p0[w];
            float sP  = den - p0, inv = 1.f / den;
            int j0 = 2*l, j1 = j0 + 1;
            float n0 = (p0*s_lnq[j0] + ln1_w[j0]*(c0 - cS) + ln1_b[j0]*sP) * inv;
            float n1 = (p0*s_lnq[j1] + ln1_w[j1]*(c1 - cS) + ln1_b[j1]*sP) * inv;
            s_sc[w*128 + j0] = n0;
            s_sc[w*128 + j1] = n1;
        }
        __syncthreads();

        // O: o = Wv @ ctxn + bv  (bf16 into s_qo16)
        if (t < 128) {
            int h = t >> 4;
            float o = dot128(W_qkv + (size_t)(2*Dn + t)*Dn, &s_sc[h*128]) + b_qkv[2*Dn + t];
            s_qo16[g][t] = f2bf(o);
        }
        __syncthreads();
    }

    //=== Tail =============================================================
    // P6a: t1 = o @ W_out^T + b_out  (d per thread, 2 batches)
    {
        int d = t & 127, gp = t >> 7;
        const float4* w4 = (const float4*)(W_out + (size_t)d * Dn);
        float a0 = 0.f, a1 = 0.f;
#pragma unroll 8
        for (int j = 0; j < 32; ++j) {
            float4 a = w4[j];
            uint2 u0 = *(const uint2*)&s_qo16[gp*2][j*4];
            uint2 u1 = *(const uint2*)&s_qo16[gp*2+1][j*4];
            float o00 = __uint_as_float(u0.x << 16), o01 = __uint_as_float(u0.x & 0xffff0000u);
            float o02 = __uint_as_float(u0.y << 16), o03 = __uint_as_float(u0.y & 0xffff0000u);
            float o10 = __uint_as_float(u1.x << 16), o11 = __uint_as_float(u1.x & 0xffff0000u);
            float o12 = __uint_as_float(u1.y << 16), o13 = __uint_as_float(u1.y & 0xffff0000u);
            a0 = fmaf(a.x,o00,a0); a0 = fmaf(a.y,o01,a0); a0 = fmaf(a.z,o02,a0); a0 = fmaf(a.w,o03,a0);
            a1 = fmaf(a.x,o10,a1); a1 = fmaf(a.y,o11,a1); a1 = fmaf(a.z,o12,a1); a1 = fmaf(a.w,o13,a1);
        }
        s_sc[(gp*2)*128 + d]   = a0 + b_out[d];
        s_sc[(gp*2+1)*128 + d] = a1 + b_out[d];
    }
    __syncthreads();

    // P6b: h = LN(t1, ln2) + q_in  -> s_A
    ln_row64<Dn>(&s_sc[wv*128], &s_A[wv*128], ln2_w, ln2_b, &s_qin[wv][0], lane);
    __syncthreads();
    // P6c: ln3h = LN(h, ln3) -> s_qin
    ln_row64<Dn>(&s_A[wv*128], &s_qin[wv][0], ln3_w, ln3_b, nullptr, lane);
    __syncthreads();

    // P6d: f1 = gelu(ln3h @ W_ff1^T + b_ff1) -> s_mem[g*512 + e]
    {
        int ep = t >> 1, gg = t & 1;
        int e0 = 2*ep, e1 = e0 + 1;
        const float4* wa = (const float4*)(W_ff1 + (size_t)e0 * Dn);
        const float4* wb = (const float4*)(W_ff1 + (size_t)e1 * Dn);
        float acc0[4] = {0,0,0,0}, acc1[4] = {0,0,0,0};
#pragma unroll 4
        for (int j = 0; j < 32; ++j) {
            float4 a = wa[j], b = wb[j];
#pragma unroll
            for (int q = 0; q < 4; ++q) {
                float4 v = *(const float4*)&s_qin[gg*4 + q][j*4];
                acc0[q] = fmaf(a.x,v.x,acc0[q]); acc0[q] = fmaf(a.y,v.y,acc0[q]);
                acc0[q] = fmaf(a.z,v.z,acc0[q]); acc0[q] = fmaf(a.w,v.w,acc0[q]);
                acc1[q] = fmaf(b.x,v.x,acc1[q]); acc1[q] = fmaf(b.y,v.y,acc1[q]);
                acc1[q] = fmaf(b.z,v.z,acc1[q]); acc1[q] = fmaf(b.w,v.w,acc1[q]);
            }
        }
#pragma unroll
        for (int q = 0; q < 4; ++q) {
            int gq = gg*4 + q;
            float v0 = acc0[q] + b_ff1[e0];
            float v1 = acc1[q] + b_ff1[e1];
            v0 = 0.5f * v0 * (1.f + erff(v0 * INV_SQRT2));
            v1 = 0.5f * v1 * (1.f + erff(v1 * INV_SQRT2));
            *(float2*)&s_mem[gq*512 + e0] = make_float2(v0, v1);
        }
    }
    __syncthreads();

    // P6e: LN(f1, ln4) in place (wave per g)
    ln_row64<DFF>(&s_mem[wv*512], &s_mem[wv*512], ln4_w, ln4_b, nullptr, lane);
    __syncthreads();

    // P6f: f2 = f1 @ W_ff2^T (K-split-4) + b_ff2 + h -> s_sc
    {
        int d = t & 127, kg = t >> 7;
        const float4* w4 = (const float4*)(W_ff2 + (size_t)d * DFF) + kg*32;
        float acc[8] = {0,0,0,0,0,0,0,0};
        for (int j = 0; j < 32; ++j) {
            float4 a = w4[j];
#pragma unroll
            for (int g2 = 0; g2 < 8; ++g2) {
                float4 v = *(const float4*)&s_mem[g2*512 + (kg*32+j)*4];
                acc[g2] = fmaf(a.x,v.x,acc[g2]); acc[g2] = fmaf(a.y,v.y,acc[g2]);
                acc[g2] = fmaf(a.z,v.z,acc[g2]); acc[g2] = fmaf(a.w,v.w,acc[g2]);
            }
        }
#pragma unroll
        for (int g2 = 0; g2 < 8; ++g2) s_mem[4096 + kg*1024 + d*8 + g2] = acc[g2];
    }
    __syncthreads();
    {
#pragma unroll
        for (int u = 0; u < 2; ++u) {
            int idx = t*2 + u; int d = idx >> 3, g2 = idx & 7;
            float v = s_mem[4096 + idx] + s_mem[5120 + idx] + s_mem[6144 + idx] + s_mem[7168 + idx];
            s_sc[g2*128 + d] = v + b_ff2[d] + s_A[g2*128 + d];
        }
    }
    __syncthreads();

    // P6g: h2 = LN(ln5) -> s_qin (reuse)
    ln_row64<Dn>(&s_sc[wv*128], &s_qin[wv][0], ln5_w, ln5_b, nullptr, lane);
    __syncthreads();

    // P6h: out = h2 @ W_head^T + b_head
    {
        int ep = t >> 1, gg = t & 1;
        int e0 = 2*ep, e1 = e0 + 1;
        const float4* wa = (const float4*)(W_head + (size_t)e0 * Dn);
        const float4* wb = (const float4*)(W_head + (size_t)e1 * Dn);
        float acc0[4] = {0,0,0,0}, acc1[4] = {0,0,0,0};
#pragma unroll 4
        for (int j = 0; j < 32; ++j) {
            float4 a = wa[j], b = wb[j];
#pragma unroll
            for (int q = 0; q < 4; ++q) {
                float4 v = *(const float4*)&s_qin[gg*4 + q][j*4];
                acc0[q] = fmaf(a.x,v.x,acc0[q]); acc0[q] = fmaf(a.y,v.y,acc0[q]);
                acc0[q] = fmaf(a.z,v.z,acc0[q]); acc0[q] = fmaf(a.w,v.w,acc0[q]);
                acc1[q] = fmaf(b.x,v.x,acc1[q]); acc1[q] = fmaf(b.y,v.y,acc1[q]);
                acc1[q] = fmaf(b.z,v.z,acc1[q]); acc1[q] = fmaf(b.w,v.w,acc1[q]);
            }
        }
#pragma unroll
        for (int q = 0; q < 4; ++q) {
            int gq = gg*4 + q;
            *(float2*)&out[(size_t)(b0+gq)*DIN + e0] =
                make_float2(acc0[q] + b_head[e0], acc1[q] + b_head[e1]);
        }
    }
}

} // namespace

extern "C" void kernel_launch(void* const* d_in, const int* in_sizes, int n_in,
                              void* d_out, int out_size, void* d_ws, size_t ws_size,
                              hipStream_t stream)
{
    const float* x      = (const float*)d_in[0];
    const float* W_in   = (const float*)d_in[1];
    const float* b_in   = (const float*)d_in[2];
    const float* pos    = (const float*)d_in[3];
    const float* mask   = (const float*)d_in[4];
    const float* mem    = (const float*)d_in[5];
    const float* ln1_w  = (const float*)d_in[6];
    const float* ln1_b  = (const float*)d_in[7];
    const float* W_qkv  = (const float*)d_in[8];
    const float* b_qkv  = (const float*)d_in[9];
    const float* W_out  = (const float*)d_in[10];
    const float* b_out  = (const float*)d_in[11];
    const float* ln2_w  = (const float*)d_in[12];
    const float* ln2_b  = (const float*)d_in[13];
    const float* ln3_w  = (const float*)d_in[14];
    const float* ln3_b  = (const float*)d_in[15];
    const float* W_ff1  = (const float*)d_in[16];
    const float* b_ff1  = (const float*)d_in[17];
    const float* ln4_w  = (const float*)d_in[18];
    const float* ln4_b  = (const float*)d_in[19];
    const float* W_ff2  = (const float*)d_in[20];
    const float* b_ff2  = (const float*)d_in[21];
    const float* ln5_w  = (const float*)d_in[22];
    const float* ln5_b  = (const float*)d_in[23];
    const float* W_head = (const float*)d_in[24];
    const float* b_head = (const float*)d_in[25];

    const int B = in_sizes[0] / DIN;   // 4096
    fused_block<<<dim3(B / Gn), dim3(512), 0, stream>>>(
        x, W_in, b_in, pos, mask, mem,
        ln1_w, ln1_b, W_qkv, b_qkv, W_out, b_out,
        ln2_w, ln2_b, ln3_w, ln3_b,
        W_ff1, b_ff1, ln4_w, ln4_b, W_ff2, b_ff2,
        ln5_w, ln5_b, W_head, b_head,
        (float*)d_out);
}